// Round 5
// baseline (136.182 us; speedup 1.0000x reference)
//
#include <hip/hip_runtime.h>
#include <math.h>

#define EMBED 1024
#define NHEAD 8
#define HDIM 128
#define TK 255
#define BATCH 4
#define LQ 128
#define BH 32

typedef __attribute__((ext_vector_type(4))) float f32x4;
typedef __attribute__((ext_vector_type(8))) short short8;
typedef __attribute__((ext_vector_type(4))) short short4v;

static __device__ __forceinline__ unsigned short f2bf(float f) {
    unsigned u = __float_as_uint(f);
    u += 0x7FFFu + ((u >> 16) & 1u);
    return (unsigned short)(u >> 16);
}
static __device__ __forceinline__ float bfbits2f(unsigned short s) {
    return __uint_as_float(((unsigned)s) << 16);
}

// ============ pack: fp32 [rows][1024] -> bf16 [rows][2048] = [hi | lo] ============
__global__ __launch_bounds__(256) void pack_all(
    const float* __restrict__ query, const float* __restrict__ key_t,
    const float* __restrict__ value, const float* __restrict__ ipw,
    const float* __restrict__ opw,
    unsigned short* __restrict__ apk, unsigned short* __restrict__ wpk)
{
    const int APKC = 2560 * 256;
    const int TOT = APKC + 4096 * 256;
    for (int idx = blockIdx.x * 256 + threadIdx.x; idx < TOT; idx += gridDim.x * 256) {
        const bool isA = idx < APKC;
        const int rel = isA ? idx : idx - APKC;
        const int row = rel >> 8, c4 = rel & 255;
        const float* src = nullptr; long srow = 0;
        unsigned short* dst;
        if (isA) {
            dst = apk + (long)row * 2048;
            if (row < 512) { src = query; srow = row; }
            else if (row < 1536) { if (row - 512 < 1020) { src = key_t; srow = row - 512; } }
            else { if (row - 1536 < 1020) { src = value; srow = row - 1536; } }
        } else {
            dst = wpk + (long)row * 2048;
            if (row < 3072) { src = ipw; srow = row; }
            else { src = opw; srow = row - 3072; }
        }
        float4 f = make_float4(0.f, 0.f, 0.f, 0.f);
        if (src) f = *(const float4*)(src + srow * 1024 + c4 * 4);
        const unsigned short h0 = f2bf(f.x), h1 = f2bf(f.y), h2 = f2bf(f.z), h3 = f2bf(f.w);
        short4v hv, lv;
        hv[0] = (short)h0; hv[1] = (short)h1; hv[2] = (short)h2; hv[3] = (short)h3;
        lv[0] = (short)f2bf(f.x - bfbits2f(h0));
        lv[1] = (short)f2bf(f.y - bfbits2f(h1));
        lv[2] = (short)f2bf(f.z - bfbits2f(h2));
        lv[3] = (short)f2bf(f.w - bfbits2f(h3));
        *(short4v*)(dst + c4 * 4) = hv;
        *(short4v*)(dst + 1024 + c4 * 4) = lv;
    }
}

// ============ packed bf16 GEMM; nkb k-blocks of 128 walking split terms ============
// nkb=24: hi.hi, lo.hi, hi.lo (3-term). nkb=16: hi.hi, lo.hi (2-term).
template<int BM, int BN>
__device__ __forceinline__ void bgemm(
    const unsigned short* __restrict__ A,
    const unsigned short* __restrict__ B,
    const float* __restrict__ bias,
    float* __restrict__ C, long ldc, float scale,
    int m0, int n0, int nkb, unsigned char* lds)
{
    constexpr int AOF = 0, BOF = BM * 256;
    constexpr int FM = BM / 32, FN = BN / 32;
    constexpr int CA = BM / 16, CB = BN / 16;
    const int t = threadIdx.x, lane = t & 63, wave = t >> 6;
    const int wm = wave >> 1, wn = wave & 1;

    f32x4 acc[FM][FN];
    #pragma unroll
    for (int i = 0; i < FM; ++i)
        #pragma unroll
        for (int j = 0; j < FN; ++j)
            #pragma unroll
            for (int e = 0; e < 4; ++e) acc[i][j][e] = 0.f;

    short8 ra[CA], rb[CB];
    #pragma unroll
    for (int c = 0; c < CA; ++c) {
        const int fi = c * 256 + t, row = fi >> 4, u = fi & 15;
        ra[c] = *(const short8*)(A + (long)(m0 + row) * 2048 + u * 8);
    }
    #pragma unroll
    for (int c = 0; c < CB; ++c) {
        const int fi = c * 256 + t, row = fi >> 4, u = fi & 15;
        rb[c] = *(const short8*)(B + (long)(n0 + row) * 2048 + u * 8);
    }

    for (int kt = 0; kt < nkb; ++kt) {
        #pragma unroll
        for (int c = 0; c < CA; ++c) {
            const int fi = c * 256 + t, row = fi >> 4, u = fi & 15;
            *(short8*)(lds + AOF + row * 256 + ((u ^ (row & 15)) << 4)) = ra[c];
        }
        #pragma unroll
        for (int c = 0; c < CB; ++c) {
            const int fi = c * 256 + t, row = fi >> 4, u = fi & 15;
            *(short8*)(lds + BOF + row * 256 + ((u ^ (row & 15)) << 4)) = rb[c];
        }
        __syncthreads();
        if (kt + 1 < nkb) {
            const int kn = kt + 1;
            const int anext = (kn & 15) << 7;                          // hi(8) lo(8) hi(8)
            const int bnext = ((kn & 7) << 7) + (kn >= 16 ? 1024 : 0); // hi hi lo
            #pragma unroll
            for (int c = 0; c < CA; ++c) {
                const int fi = c * 256 + t, row = fi >> 4, u = fi & 15;
                ra[c] = *(const short8*)(A + (long)(m0 + row) * 2048 + anext + u * 8);
            }
            #pragma unroll
            for (int c = 0; c < CB; ++c) {
                const int fi = c * 256 + t, row = fi >> 4, u = fi & 15;
                rb[c] = *(const short8*)(B + (long)(n0 + row) * 2048 + bnext + u * 8);
            }
        }
        #pragma unroll
        for (int ks = 0; ks < 4; ++ks) {
            short8 af[FM], bg[FN];
            #pragma unroll
            for (int fm = 0; fm < FM; ++fm) {
                const int row = wm * (BM / 2) + fm * 16 + (lane & 15);
                const int u = (ks * 4 + (lane >> 4)) ^ (row & 15);
                af[fm] = *(const short8*)(lds + AOF + row * 256 + (u << 4));
            }
            #pragma unroll
            for (int fn = 0; fn < FN; ++fn) {
                const int row = wn * (BN / 2) + fn * 16 + (lane & 15);
                const int u = (ks * 4 + (lane >> 4)) ^ (row & 15);
                bg[fn] = *(const short8*)(lds + BOF + row * 256 + (u << 4));
            }
            #pragma unroll
            for (int fm = 0; fm < FM; ++fm)
                #pragma unroll
                for (int fn = 0; fn < FN; ++fn)
                    acc[fm][fn] = __builtin_amdgcn_mfma_f32_16x16x32_bf16(af[fm], bg[fn], acc[fm][fn], 0, 0, 0);
        }
        __syncthreads();
    }

    #pragma unroll
    for (int fm = 0; fm < FM; ++fm)
        #pragma unroll
        for (int i = 0; i < 4; ++i) {
            const int m = m0 + wm * (BM / 2) + fm * 16 + ((lane >> 4) << 2) + i;
            #pragma unroll
            for (int fn = 0; fn < FN; ++fn) {
                const int n = n0 + wn * (BN / 2) + fn * 16 + (lane & 15);
                float v = acc[fm][fn][i];
                if (bias) v += bias[n];
                C[(long)m * ldc + n] = v * scale;
            }
        }
}

__global__ __launch_bounds__(256) void qkvb_kernel(
    const unsigned short* __restrict__ apk, const unsigned short* __restrict__ wpk,
    const float* __restrict__ ipb,
    float* __restrict__ qp, float* __restrict__ kp, float* __restrict__ vp, float qscale)
{
    __shared__ __align__(16) unsigned char lds[(64 + 64) * 256];
    const int y = blockIdx.y;
    const unsigned short* A; const unsigned short* B; const float* bias; float* C;
    float scale; int m0; int nkb;
    if (y < 8)       { A = apk;                m0 = y * 64;        B = wpk;                bias = ipb;        C = qp; scale = qscale; nkb = 24; }
    else if (y < 24) { A = apk + 512L * 2048;  m0 = (y - 8) * 64;  B = wpk + 1024L * 2048; bias = ipb + 1024; C = kp; scale = 1.f;    nkb = 24; }
    else             { A = apk + 1536L * 2048; m0 = (y - 24) * 64; B = wpk + 2048L * 2048; bias = ipb + 2048; C = vp; scale = 1.f;    nkb = 16; }
    bgemm<64, 64>(A, B, bias, C, 1024, scale, m0, blockIdx.x * 64, nkb, lds);
}

__global__ __launch_bounds__(256) void outprojb_kernel(
    const unsigned short* __restrict__ apk2, const unsigned short* __restrict__ wpk,
    const float* __restrict__ opb, float* __restrict__ out)
{
    __shared__ __align__(16) unsigned char lds[(32 + 64) * 256];
    bgemm<32, 64>(apk2, wpk + 3072L * 2048, opb, out, 1024, 1.f,
                  blockIdx.y * 32, blockIdx.x * 64, 16, lds);
}

// ============ ktree: k~[b][n][e] = kp[n][e] + k~[left] + k~[right], bottom-up ============
// blocks (cc, b): each owns cols cc*128..+127 of batch b. ktil [4][256][1024] fp32.
__global__ __launch_bounds__(256) void ktree_kernel(
    const float* __restrict__ kp, const int* __restrict__ indices,
    float* __restrict__ ktil)
{
    const int cc = blockIdx.x, b = blockIdx.y;
    const int t = threadIdx.x;
    const int c4 = t & 31, np = t >> 5;  // 32 float4-cols, 8-way node parallel
    __shared__ int rs[256], cs[256];
    if (t < TK) {
        rs[t] = indices[(b * TK + t) * 2 + 0];
        cs[t] = indices[(b * TK + t) * 2 + 1];
    }
    float* kt = ktil + ((long)b * 256) * 1024 + cc * 128;
    // copy (node 255 -> zeros)
    for (int n = np; n < 256; n += 8) {
        float4 f = make_float4(0.f, 0.f, 0.f, 0.f);
        if (n < TK) f = *(const float4*)(kp + (long)(n * 4 + b) * 1024 + cc * 128 + c4 * 4);
        *(float4*)(kt + (long)n * 1024 + c4 * 4) = f;
    }
    __syncthreads();
    for (int w = 2; w <= 128; w <<= 1) {
        for (int n = np; n < TK; n += 8) {
            const int r = rs[n], c = cs[n];
            if (c - r + 1 == w) {
                const int mid = (r + c) >> 1;
                const int rch = n + 2 * (mid - r) + 2;
                float4 me = *(const float4*)(kt + (long)n * 1024 + c4 * 4);
                float4 lf = *(const float4*)(kt + (long)(n + 1) * 1024 + c4 * 4);
                float4 rg = *(const float4*)(kt + (long)rch * 1024 + c4 * 4);
                me.x += lf.x + rg.x; me.y += lf.y + rg.y;
                me.z += lf.z + rg.z; me.w += lf.w + rg.w;
                *(float4*)(kt + (long)n * 1024 + c4 * 4) = me;
            }
        }
        __syncthreads();
    }
}

// ============ fused attention: per (b,h,qhalf). S=Q.k~^T -> softmax -> P.V -> packed bf16 ====
// LDS: QH 16K | QL 16K | KH 16K (Vt overlay) | KL 16K | PH 32K | PL 32K | RED 1K | INV 256B
#define F_QH 0
#define F_QL 16384
#define F_KH 32768
#define F_KL 49152
#define F_PH 65536
#define F_PL 98304
#define F_RED 131072
#define F_INV 132096

__global__ __launch_bounds__(256, 1) void fused_attn_kernel(
    const float* __restrict__ qp, const float* __restrict__ ktil,
    const float* __restrict__ vp, unsigned short* __restrict__ apk2)
{
    __shared__ __align__(16) unsigned char lds[132352];
    const int blk = blockIdx.x;
    const int qh = blk & 1, bh = blk >> 1, b = bh >> 3, h = bh & 7;
    const int t = threadIdx.x, lane = t & 63, wave = t >> 6;
    const int wm = wave >> 1, wn = wave & 1;
    float* red = (float*)(lds + F_RED);   // [2 phase][2 wn][64 row]
    float* inv = (float*)(lds + F_INV);   // [64]

    // ---- stage Q (64 rows x 128 cols) -> hi/lo, pitch 256B, unit ^= row&15
    {
        const int c4 = t & 31, r8 = t >> 5;
        #pragma unroll
        for (int rr = 0; rr < 8; ++rr) {
            const int row = r8 + rr * 8;
            const int tq = qh * 64 + row;
            float4 f = *(const float4*)(qp + (long)(tq * 4 + b) * 1024 + h * 128 + c4 * 4);
            const unsigned short h0 = f2bf(f.x), h1 = f2bf(f.y), h2 = f2bf(f.z), h3 = f2bf(f.w);
            short4v hv, lv;
            hv[0] = (short)h0; hv[1] = (short)h1; hv[2] = (short)h2; hv[3] = (short)h3;
            lv[0] = (short)f2bf(f.x - bfbits2f(h0));
            lv[1] = (short)f2bf(f.y - bfbits2f(h1));
            lv[2] = (short)f2bf(f.z - bfbits2f(h2));
            lv[3] = (short)f2bf(f.w - bfbits2f(h3));
            const int byte = row * 256 + ((((c4 >> 1) ^ (row & 15)) << 4) | ((c4 & 1) << 3));
            *(short4v*)(lds + F_QH + byte) = hv;
            *(short4v*)(lds + F_QL + byte) = lv;
        }
    }

    // ---- QK^T: acc[nb][fm][fn], 3-term (q hi+lo, k~ hi+lo -> hh, lh, hl)
    f32x4 acc[4][2][2];
    #pragma unroll
    for (int nb = 0; nb < 4; ++nb)
        #pragma unroll
        for (int i = 0; i < 2; ++i)
            #pragma unroll
            for (int j = 0; j < 2; ++j)
                #pragma unroll
                for (int e = 0; e < 4; ++e) acc[nb][i][j][e] = 0.f;

    #pragma unroll
    for (int nb = 0; nb < 4; ++nb) {
        __syncthreads();
        {   // stage k~ block (64 nodes x 128 dims) -> hi/lo
            const int c4 = t & 31, r8 = t >> 5;
            #pragma unroll
            for (int rr = 0; rr < 8; ++rr) {
                const int nl = r8 + rr * 8;
                const int node = nb * 64 + nl;
                float4 f = *(const float4*)(ktil + ((long)b * 256 + node) * 1024 + h * 128 + c4 * 4);
                const unsigned short h0 = f2bf(f.x), h1 = f2bf(f.y), h2 = f2bf(f.z), h3 = f2bf(f.w);
                short4v hv, lv;
                hv[0] = (short)h0; hv[1] = (short)h1; hv[2] = (short)h2; hv[3] = (short)h3;
                lv[0] = (short)f2bf(f.x - bfbits2f(h0));
                lv[1] = (short)f2bf(f.y - bfbits2f(h1));
                lv[2] = (short)f2bf(f.z - bfbits2f(h2));
                lv[3] = (short)f2bf(f.w - bfbits2f(h3));
                const int byte = nl * 256 + ((((c4 >> 1) ^ (nl & 15)) << 4) | ((c4 & 1) << 3));
                *(short4v*)(lds + F_KH + byte) = hv;
                *(short4v*)(lds + F_KL + byte) = lv;
            }
        }
        __syncthreads();
        #pragma unroll
        for (int ks = 0; ks < 4; ++ks) {
            short8 ah[2], al[2], bh_[2], bl[2];
            #pragma unroll
            for (int fm = 0; fm < 2; ++fm) {
                const int row = wm * 32 + fm * 16 + (lane & 15);
                const int byte = row * 256 + (((ks * 4 + (lane >> 4)) ^ (row & 15)) << 4);
                ah[fm] = *(const short8*)(lds + F_QH + byte);
                al[fm] = *(const short8*)(lds + F_QL + byte);
            }
            #pragma unroll
            for (int fn = 0; fn < 2; ++fn) {
                const int row = wn * 32 + fn * 16 + (lane & 15);
                const int byte = row * 256 + (((ks * 4 + (lane >> 4)) ^ (row & 15)) << 4);
                bh_[fn] = *(const short8*)(lds + F_KH + byte);
                bl[fn] = *(const short8*)(lds + F_KL + byte);
            }
            #pragma unroll
            for (int fm = 0; fm < 2; ++fm)
                #pragma unroll
                for (int fn = 0; fn < 2; ++fn) {
                    acc[nb][fm][fn] = __builtin_amdgcn_mfma_f32_16x16x32_bf16(ah[fm], bh_[fn], acc[nb][fm][fn], 0, 0, 0);
                    acc[nb][fm][fn] = __builtin_amdgcn_mfma_f32_16x16x32_bf16(al[fm], bh_[fn], acc[nb][fm][fn], 0, 0, 0);
                    acc[nb][fm][fn] = __builtin_amdgcn_mfma_f32_16x16x32_bf16(ah[fm], bl[fn], acc[nb][fm][fn], 0, 0, 0);
                }
        }
    }

    // ---- softmax over 256 cols (col>=255 masked)
    float pmax[2][4];
    #pragma unroll
    for (int fm = 0; fm < 2; ++fm)
        #pragma unroll
        for (int i = 0; i < 4; ++i) pmax[fm][i] = -1e30f;
    #pragma unroll
    for (int nb = 0; nb < 4; ++nb)
        #pragma unroll
        for (int fm = 0; fm < 2; ++fm)
            #pragma unroll
            for (int fn = 0; fn < 2; ++fn)
                #pragma unroll
                for (int i = 0; i < 4; ++i) {
                    const int col = nb * 64 + wn * 32 + fn * 16 + (lane & 15);
                    const float s = (col < TK) ? acc[nb][fm][fn][i] : -1e30f;
                    pmax[fm][i] = fmaxf(pmax[fm][i], s);
                }
    #pragma unroll
    for (int off = 1; off < 16; off <<= 1)
        #pragma unroll
        for (int fm = 0; fm < 2; ++fm)
            #pragma unroll
            for (int i = 0; i < 4; ++i) pmax[fm][i] = fmaxf(pmax[fm][i], __shfl_xor(pmax[fm][i], off));
    if ((lane & 15) == 0) {
        #pragma unroll
        for (int fm = 0; fm < 2; ++fm)
            #pragma unroll
            for (int i = 0; i < 4; ++i) {
                const int row = wm * 32 + fm * 16 + ((lane >> 4) << 2) + i;
                red[wn * 64 + row] = pmax[fm][i];
            }
    }
    __syncthreads();
    float rm[2][4];
    #pragma unroll
    for (int fm = 0; fm < 2; ++fm)
        #pragma unroll
        for (int i = 0; i < 4; ++i) {
            const int row = wm * 32 + fm * 16 + ((lane >> 4) << 2) + i;
            rm[fm][i] = fmaxf(red[row], red[64 + row]);
        }
    // exp, write P (unnormalized), partial sums
    float psum[2][4] = {{0.f, 0.f, 0.f, 0.f}, {0.f, 0.f, 0.f, 0.f}};
    #pragma unroll
    for (int nb = 0; nb < 4; ++nb)
        #pragma unroll
        for (int fm = 0; fm < 2; ++fm)
            #pragma unroll
            for (int fn = 0; fn < 2; ++fn)
                #pragma unroll
                for (int i = 0; i < 4; ++i) {
                    const int col = nb * 64 + wn * 32 + fn * 16 + (lane & 15);
                    const int row = wm * 32 + fm * 16 + ((lane >> 4) << 2) + i;
                    float p = 0.f;
                    if (col < TK) p = __expf(acc[nb][fm][fn][i] - rm[fm][i]);
                    psum[fm][i] += p;
                    const unsigned short hp = f2bf(p);
                    const unsigned short lp = f2bf(p - bfbits2f(hp));
                    const int u = ((col >> 3) ^ ((row & 15) << 1));
                    const int byte = row * 512 + (u << 4) + (col & 7) * 2;
                    *(unsigned short*)(lds + F_PH + byte) = hp;
                    *(unsigned short*)(lds + F_PL + byte) = lp;
                }
    #pragma unroll
    for (int off = 1; off < 16; off <<= 1)
        #pragma unroll
        for (int fm = 0; fm < 2; ++fm)
            #pragma unroll
            for (int i = 0; i < 4; ++i) psum[fm][i] += __shfl_xor(psum[fm][i], off);
    if ((lane & 15) == 0) {
        #pragma unroll
        for (int fm = 0; fm < 2; ++fm)
            #pragma unroll
            for (int i = 0; i < 4; ++i) {
                const int row = wm * 32 + fm * 16 + ((lane >> 4) << 2) + i;
                red[128 + wn * 64 + row] = psum[fm][i];
            }
    }
    __syncthreads();
    if (wn == 0 && (lane & 15) == 0) {
        #pragma unroll
        for (int fm = 0; fm < 2; ++fm)
            #pragma unroll
            for (int i = 0; i < 4; ++i) {
                const int row = wm * 32 + fm * 16 + ((lane >> 4) << 2) + i;
                inv[row] = 1.f / (red[128 + row] + red[128 + 64 + row]);
            }
    }

    // ---- PV: O = P . V, 2-term (P hi+lo, V hi). Vt staged [128 d][64 n] in KH region.
    f32x4 accO[2][4];
    #pragma unroll
    for (int fm = 0; fm < 2; ++fm)
        #pragma unroll
        for (int fn = 0; fn < 4; ++fn)
            #pragma unroll
            for (int e = 0; e < 4; ++e) accO[fm][fn][e] = 0.f;

    #pragma unroll
    for (int nb = 0; nb < 4; ++nb) {
        __syncthreads();
        {   // transpose-stage V hi: Vt[d][n], pitch 128B, unit ^= d&7
            const int c4 = t & 31, r8 = t >> 5;
            #pragma unroll
            for (int rr = 0; rr < 8; ++rr) {
                const int nl = r8 + rr * 8;
                const int node = nb * 64 + nl;
                float4 f = make_float4(0.f, 0.f, 0.f, 0.f);
                if (node < TK) f = *(const float4*)(vp + (long)(node * 4 + b) * 1024 + h * 128 + c4 * 4);
                const float fa[4] = {f.x, f.y, f.z, f.w};
                #pragma unroll
                for (int j = 0; j < 4; ++j) {
                    const int d = c4 * 4 + j;
                    const int byte = d * 128 + ((((nl >> 3) ^ (d & 7)) << 4) | ((nl & 7) << 1));
                    *(unsigned short*)(lds + F_KH + byte) = f2bf(fa[j]);
                }
            }
        }
        __syncthreads();
        #pragma unroll
        for (int ks = 0; ks < 2; ++ks) {
            short8 pa[2], pl[2], vb[4];
            #pragma unroll
            for (int fm = 0; fm < 2; ++fm) {
                const int row = wm * 32 + fm * 16 + (lane & 15);
                const int u = (nb * 8 + ks * 4 + (lane >> 4)) ^ ((row & 15) << 1);
                const int byte = row * 512 + (u << 4);
                pa[fm] = *(const short8*)(lds + F_PH + byte);
                pl[fm] = *(const short8*)(lds + F_PL + byte);
            }
            #pragma unroll
            for (int fn = 0; fn < 4; ++fn) {
                const int d = wn * 64 + fn * 16 + (lane & 15);
                const int u = (ks * 4 + (lane >> 4)) ^ (d & 7);
                const int byte = d * 128 + (u << 4);
                vb[fn] = *(const short8*)(lds + F_KH + byte);
            }
            #pragma unroll
            for (int fm = 0; fm < 2; ++fm)
                #pragma unroll
                for (int fn = 0; fn < 4; ++fn) {
                    accO[fm][fn] = __builtin_amdgcn_mfma_f32_16x16x32_bf16(pa[fm], vb[fn], accO[fm][fn], 0, 0, 0);
                    accO[fm][fn] = __builtin_amdgcn_mfma_f32_16x16x32_bf16(pl[fm], vb[fn], accO[fm][fn], 0, 0, 0);
                }
        }
    }

    // ---- epilogue: normalize + write packed bf16 [hi|lo] attn rows directly
    __syncthreads();
    #pragma unroll
    for (int fm = 0; fm < 2; ++fm)
        #pragma unroll
        for (int i = 0; i < 4; ++i) {
            const int row = wm * 32 + fm * 16 + ((lane >> 4) << 2) + i;
            const float iv = inv[row];
            const int arow = (qh * 64 + row) * 4 + b;
            #pragma unroll
            for (int fn = 0; fn < 4; ++fn) {
                const int col = h * 128 + wn * 64 + fn * 16 + (lane & 15);
                const float val = accO[fm][fn][i] * iv;
                const unsigned short hv = f2bf(val);
                const unsigned short lv = f2bf(val - bfbits2f(hv));
                apk2[(long)arow * 2048 + col] = hv;
                apk2[(long)arow * 2048 + 1024 + col] = lv;
            }
        }
}

extern "C" void kernel_launch(void* const* d_in, const int* in_sizes, int n_in,
                              void* d_out, int out_size, void* d_ws, size_t ws_size,
                              hipStream_t stream) {
    const float* query   = (const float*)d_in[0];
    const float* key_t   = (const float*)d_in[1];
    const float* value   = (const float*)d_in[2];
    const int*   indices = (const int*)d_in[3];
    const float* ipw     = (const float*)d_in[4];
    const float* ipb     = (const float*)d_in[5];
    const float* opw     = (const float*)d_in[6];
    const float* opb     = (const float*)d_in[7];
    float* out = (float*)d_out;

    float* ws = (float*)d_ws;
    float* kp   = ws;                        // [1024][1024]
    float* vp   = kp + 1048576;              // [1024][1024]
    float* qp   = vp + 1048576;              // [512][1024]
    float* ktil = qp + 524288;               // [4][256][1024]
    unsigned short* apk  = (unsigned short*)(ktil + 1048576);  // [2560][2048]
    unsigned short* wpk  = apk + 2560L * 2048;                 // [4096][2048]
    unsigned short* apk2 = apk;              // overlay (apk dead after qkvb)

    const float qscale = 0.08838834764831843f;  // 128^-0.5

    pack_all<<<dim3(2048), 256, 0, stream>>>(query, key_t, value, ipw, opw, apk, wpk);

    qkvb_kernel<<<dim3(16, 40), 256, 0, stream>>>(apk, wpk, ipb, qp, kp, vp, qscale);

    ktree_kernel<<<dim3(8, 4), 256, 0, stream>>>(kp, indices, ktil);

    fused_attn_kernel<<<dim3(64), 256, 0, stream>>>(qp, ktil, vp, apk2);

    outprojb_kernel<<<dim3(16, 16), 256, 0, stream>>>(apk2, wpk, opb, out);
}

// Round 6
// 100.933 us; speedup vs baseline: 1.3492x; 1.3492x over previous
//
#include <hip/hip_runtime.h>
#include <math.h>

#define EMBED 1024
#define NHEAD 8
#define HDIM 128
#define TK 255
#define BATCH 4
#define LQ 128
#define BH 32

typedef __attribute__((ext_vector_type(4))) float f32x4;
typedef __attribute__((ext_vector_type(8))) short short8;
typedef __attribute__((ext_vector_type(4))) short short4v;

static __device__ __forceinline__ unsigned short f2bf(float f) {
    unsigned u = __float_as_uint(f);
    u += 0x7FFFu + ((u >> 16) & 1u);
    return (unsigned short)(u >> 16);
}
static __device__ __forceinline__ float bfbits2f(unsigned short s) {
    return __uint_as_float(((unsigned)s) << 16);
}

// ============ pack: fp32 [rows][1024] -> bf16 [rows][2048] = [hi | lo] ============
__global__ __launch_bounds__(256) void pack_all(
    const float* __restrict__ query, const float* __restrict__ key_t,
    const float* __restrict__ value, const float* __restrict__ ipw,
    const float* __restrict__ opw,
    unsigned short* __restrict__ apk, unsigned short* __restrict__ wpk)
{
    const int APKC = 2560 * 256;
    const int TOT = APKC + 4096 * 256;
    for (int idx = blockIdx.x * 256 + threadIdx.x; idx < TOT; idx += gridDim.x * 256) {
        const bool isA = idx < APKC;
        const int rel = isA ? idx : idx - APKC;
        const int row = rel >> 8, c4 = rel & 255;
        const float* src = nullptr; long srow = 0;
        unsigned short* dst;
        if (isA) {
            dst = apk + (long)row * 2048;
            if (row < 512) { src = query; srow = row; }
            else if (row < 1536) { if (row - 512 < 1020) { src = key_t; srow = row - 512; } }
            else { if (row - 1536 < 1020) { src = value; srow = row - 1536; } }
        } else {
            dst = wpk + (long)row * 2048;
            if (row < 3072) { src = ipw; srow = row; }
            else { src = opw; srow = row - 3072; }
        }
        float4 f = make_float4(0.f, 0.f, 0.f, 0.f);
        if (src) f = *(const float4*)(src + srow * 1024 + c4 * 4);
        const unsigned short h0 = f2bf(f.x), h1 = f2bf(f.y), h2 = f2bf(f.z), h3 = f2bf(f.w);
        short4v hv, lv;
        hv[0] = (short)h0; hv[1] = (short)h1; hv[2] = (short)h2; hv[3] = (short)h3;
        lv[0] = (short)f2bf(f.x - bfbits2f(h0));
        lv[1] = (short)f2bf(f.y - bfbits2f(h1));
        lv[2] = (short)f2bf(f.z - bfbits2f(h2));
        lv[3] = (short)f2bf(f.w - bfbits2f(h3));
        *(short4v*)(dst + c4 * 4) = hv;
        *(short4v*)(dst + 1024 + c4 * 4) = lv;
    }
}

// ============ packed bf16 GEMM; nkb k-blocks of 128 walking split terms ============
template<int BM, int BN>
__device__ __forceinline__ void bgemm(
    const unsigned short* __restrict__ A,
    const unsigned short* __restrict__ B,
    const float* __restrict__ bias,
    float* __restrict__ C, long ldc, float scale,
    int m0, int n0, int nkb, unsigned char* lds)
{
    constexpr int AOF = 0, BOF = BM * 256;
    constexpr int FM = BM / 32, FN = BN / 32;
    constexpr int CA = BM / 16, CB = BN / 16;
    const int t = threadIdx.x, lane = t & 63, wave = t >> 6;
    const int wm = wave >> 1, wn = wave & 1;

    f32x4 acc[FM][FN];
    #pragma unroll
    for (int i = 0; i < FM; ++i)
        #pragma unroll
        for (int j = 0; j < FN; ++j)
            #pragma unroll
            for (int e = 0; e < 4; ++e) acc[i][j][e] = 0.f;

    short8 ra[CA], rb[CB];
    #pragma unroll
    for (int c = 0; c < CA; ++c) {
        const int fi = c * 256 + t, row = fi >> 4, u = fi & 15;
        ra[c] = *(const short8*)(A + (long)(m0 + row) * 2048 + u * 8);
    }
    #pragma unroll
    for (int c = 0; c < CB; ++c) {
        const int fi = c * 256 + t, row = fi >> 4, u = fi & 15;
        rb[c] = *(const short8*)(B + (long)(n0 + row) * 2048 + u * 8);
    }

    for (int kt = 0; kt < nkb; ++kt) {
        #pragma unroll
        for (int c = 0; c < CA; ++c) {
            const int fi = c * 256 + t, row = fi >> 4, u = fi & 15;
            *(short8*)(lds + AOF + row * 256 + ((u ^ (row & 15)) << 4)) = ra[c];
        }
        #pragma unroll
        for (int c = 0; c < CB; ++c) {
            const int fi = c * 256 + t, row = fi >> 4, u = fi & 15;
            *(short8*)(lds + BOF + row * 256 + ((u ^ (row & 15)) << 4)) = rb[c];
        }
        __syncthreads();
        if (kt + 1 < nkb) {
            const int kn = kt + 1;
            const int anext = (kn & 15) << 7;                          // hi(8) lo(8) hi(8)
            const int bnext = ((kn & 7) << 7) + (kn >= 16 ? 1024 : 0); // hi hi lo
            #pragma unroll
            for (int c = 0; c < CA; ++c) {
                const int fi = c * 256 + t, row = fi >> 4, u = fi & 15;
                ra[c] = *(const short8*)(A + (long)(m0 + row) * 2048 + anext + u * 8);
            }
            #pragma unroll
            for (int c = 0; c < CB; ++c) {
                const int fi = c * 256 + t, row = fi >> 4, u = fi & 15;
                rb[c] = *(const short8*)(B + (long)(n0 + row) * 2048 + bnext + u * 8);
            }
        }
        #pragma unroll
        for (int ks = 0; ks < 4; ++ks) {
            short8 af[FM], bg[FN];
            #pragma unroll
            for (int fm = 0; fm < FM; ++fm) {
                const int row = wm * (BM / 2) + fm * 16 + (lane & 15);
                const int u = (ks * 4 + (lane >> 4)) ^ (row & 15);
                af[fm] = *(const short8*)(lds + AOF + row * 256 + (u << 4));
            }
            #pragma unroll
            for (int fn = 0; fn < FN; ++fn) {
                const int row = wn * (BN / 2) + fn * 16 + (lane & 15);
                const int u = (ks * 4 + (lane >> 4)) ^ (row & 15);
                bg[fn] = *(const short8*)(lds + BOF + row * 256 + (u << 4));
            }
            #pragma unroll
            for (int fm = 0; fm < FM; ++fm)
                #pragma unroll
                for (int fn = 0; fn < FN; ++fn)
                    acc[fm][fn] = __builtin_amdgcn_mfma_f32_16x16x32_bf16(af[fm], bg[fn], acc[fm][fn], 0, 0, 0);
        }
        __syncthreads();
    }

    #pragma unroll
    for (int fm = 0; fm < FM; ++fm)
        #pragma unroll
        for (int i = 0; i < 4; ++i) {
            const int m = m0 + wm * (BM / 2) + fm * 16 + ((lane >> 4) << 2) + i;
            #pragma unroll
            for (int fn = 0; fn < FN; ++fn) {
                const int n = n0 + wn * (BN / 2) + fn * 16 + (lane & 15);
                float v = acc[fm][fn][i];
                if (bias) v += bias[n];
                C[(long)m * ldc + n] = v * scale;
            }
        }
}

__global__ __launch_bounds__(256) void qkvb_kernel(
    const unsigned short* __restrict__ apk, const unsigned short* __restrict__ wpk,
    const float* __restrict__ ipb,
    float* __restrict__ qp, float* __restrict__ kp, float* __restrict__ vp, float qscale)
{
    __shared__ __align__(16) unsigned char lds[(64 + 64) * 256];
    const int y = blockIdx.y;
    const unsigned short* A; const unsigned short* B; const float* bias; float* C;
    float scale; int m0; int nkb;
    if (y < 8)       { A = apk;                m0 = y * 64;        B = wpk;                bias = ipb;        C = qp; scale = qscale; nkb = 24; }
    else if (y < 24) { A = apk + 512L * 2048;  m0 = (y - 8) * 64;  B = wpk + 1024L * 2048; bias = ipb + 1024; C = kp; scale = 1.f;    nkb = 24; }
    else             { A = apk + 1536L * 2048; m0 = (y - 24) * 64; B = wpk + 2048L * 2048; bias = ipb + 2048; C = vp; scale = 1.f;    nkb = 16; }
    bgemm<64, 64>(A, B, bias, C, 1024, scale, m0, blockIdx.x * 64, nkb, lds);
}

__global__ __launch_bounds__(256) void outprojb_kernel(
    const unsigned short* __restrict__ apk2, const unsigned short* __restrict__ wpk,
    const float* __restrict__ opb, float* __restrict__ out)
{
    __shared__ __align__(16) unsigned char lds[(32 + 64) * 256];
    bgemm<32, 64>(apk2, wpk + 3072L * 2048, opb, out, 1024, 1.f,
                  blockIdx.y * 32, blockIdx.x * 64, 16, lds);
}

// ============ ksuffix: sbuf[b][n][e] = sum_{m=n..254} kp[(m*4+b)][e], sbuf[b][255][e]=0 ====
// Two-level scan: 8 segments of 32 nodes, 32 cols per block. Grid (32, 4).
__global__ __launch_bounds__(256) void ksuffix_kernel(
    const float* __restrict__ kp, float* __restrict__ sbuf)
{
    const int b = blockIdx.y;
    const int cl = threadIdx.x & 31;
    const int e = blockIdx.x * 32 + cl;
    const int seg = threadIdx.x >> 5;       // 0..7
    __shared__ float tot[8][33];
    float acc = 0.f;
    const int nhi = seg * 32 + 31;          // seg 7 covers 224..255 (node 255 = 0)
    #pragma unroll 8
    for (int i = 0; i < 32; ++i) {
        const int n = nhi - i;
        float v = 0.f;
        if (n < TK) v = kp[(long)(n * 4 + b) * 1024 + e];
        acc += v;
        sbuf[((long)b * 256 + n) * 1024 + e] = acc;
    }
    tot[seg][cl] = acc;
    __syncthreads();
    float add = 0.f;
    #pragma unroll
    for (int s = 0; s < 8; ++s) if (s > seg) add += tot[s][cl];
    if (seg < 7) {
        #pragma unroll 8
        for (int i = 0; i < 32; ++i) {
            const int n = seg * 32 + i;
            sbuf[((long)b * 256 + n) * 1024 + e] += add;
        }
    }
}

// ============ fused attention: per (b,h,qhalf). k~_n = S_n - S_{onode}; S=Q.k~^T -> softmax -> P.V ====
// LDS: QH 16K | QL 16K | KH 16K (Vt overlay) | KL 16K | PH 32K | PL 32K | RED 1K | INV 256B
#define F_QH 0
#define F_QL 16384
#define F_KH 32768
#define F_KL 49152
#define F_PH 65536
#define F_PL 98304
#define F_RED 131072
#define F_INV 132096

__global__ __launch_bounds__(256, 1) void fused_attn_kernel(
    const float* __restrict__ qp, const float* __restrict__ sbuf,
    const float* __restrict__ vp, const int* __restrict__ indices,
    unsigned short* __restrict__ apk2)
{
    __shared__ __align__(16) unsigned char lds[132352];
    __shared__ int onode[256];
    const int blk = blockIdx.x;
    const int qh = blk & 1, bh = blk >> 1, b = bh >> 3, h = bh & 7;
    const int t = threadIdx.x, lane = t & 63, wave = t >> 6;
    const int wm = wave >> 1, wn = wave & 1;
    float* red = (float*)(lds + F_RED);
    float* inv = (float*)(lds + F_INV);

    // ---- onode table: end-of-subtree + 1 (preorder contiguity)
    if (t < TK) {
        const int r0 = indices[(b * TK + t) * 2 + 0];
        const int c0 = indices[(b * TK + t) * 2 + 1];
        onode[t] = t + 2 * (c0 - r0) + 1;
    } else if (t < 256) {
        onode[t] = 255;   // k~ = S255 - S255 = 0
    }

    // ---- stage Q (64 rows x 128 cols) -> hi/lo, pitch 256B, unit ^= row&15
    {
        const int c4 = t & 31, r8 = t >> 5;
        #pragma unroll
        for (int rr = 0; rr < 8; ++rr) {
            const int row = r8 + rr * 8;
            const int tq = qh * 64 + row;
            float4 f = *(const float4*)(qp + (long)(tq * 4 + b) * 1024 + h * 128 + c4 * 4);
            const unsigned short h0 = f2bf(f.x), h1 = f2bf(f.y), h2 = f2bf(f.z), h3 = f2bf(f.w);
            short4v hv, lv;
            hv[0] = (short)h0; hv[1] = (short)h1; hv[2] = (short)h2; hv[3] = (short)h3;
            lv[0] = (short)f2bf(f.x - bfbits2f(h0));
            lv[1] = (short)f2bf(f.y - bfbits2f(h1));
            lv[2] = (short)f2bf(f.z - bfbits2f(h2));
            lv[3] = (short)f2bf(f.w - bfbits2f(h3));
            const int byte = row * 256 + ((((c4 >> 1) ^ (row & 15)) << 4) | ((c4 & 1) << 3));
            *(short4v*)(lds + F_QH + byte) = hv;
            *(short4v*)(lds + F_QL + byte) = lv;
        }
    }

    // ---- QK^T: acc[nb][fm][fn], 3-term
    f32x4 acc[4][2][2];
    #pragma unroll
    for (int nb = 0; nb < 4; ++nb)
        #pragma unroll
        for (int i = 0; i < 2; ++i)
            #pragma unroll
            for (int j = 0; j < 2; ++j)
                #pragma unroll
                for (int e = 0; e < 4; ++e) acc[nb][i][j][e] = 0.f;

    #pragma unroll
    for (int nb = 0; nb < 4; ++nb) {
        __syncthreads();
        {   // stage k~ block: k~_node = S[node] - S[onode[node]]
            const int c4 = t & 31, r8 = t >> 5;
            const float* sb = sbuf + (long)b * 256 * 1024 + h * 128 + c4 * 4;
            #pragma unroll
            for (int rr = 0; rr < 8; ++rr) {
                const int nl = r8 + rr * 8;
                const int node = nb * 64 + nl;
                float4 f0 = *(const float4*)(sb + (long)node * 1024);
                float4 f1 = *(const float4*)(sb + (long)onode[node] * 1024);
                float4 f = make_float4(f0.x - f1.x, f0.y - f1.y, f0.z - f1.z, f0.w - f1.w);
                const unsigned short h0 = f2bf(f.x), h1 = f2bf(f.y), h2 = f2bf(f.z), h3 = f2bf(f.w);
                short4v hv, lv;
                hv[0] = (short)h0; hv[1] = (short)h1; hv[2] = (short)h2; hv[3] = (short)h3;
                lv[0] = (short)f2bf(f.x - bfbits2f(h0));
                lv[1] = (short)f2bf(f.y - bfbits2f(h1));
                lv[2] = (short)f2bf(f.z - bfbits2f(h2));
                lv[3] = (short)f2bf(f.w - bfbits2f(h3));
                const int byte = nl * 256 + ((((c4 >> 1) ^ (nl & 15)) << 4) | ((c4 & 1) << 3));
                *(short4v*)(lds + F_KH + byte) = hv;
                *(short4v*)(lds + F_KL + byte) = lv;
            }
        }
        __syncthreads();
        #pragma unroll
        for (int ks = 0; ks < 4; ++ks) {
            short8 ah[2], al[2], bh_[2], bl[2];
            #pragma unroll
            for (int fm = 0; fm < 2; ++fm) {
                const int row = wm * 32 + fm * 16 + (lane & 15);
                const int byte = row * 256 + (((ks * 4 + (lane >> 4)) ^ (row & 15)) << 4);
                ah[fm] = *(const short8*)(lds + F_QH + byte);
                al[fm] = *(const short8*)(lds + F_QL + byte);
            }
            #pragma unroll
            for (int fn = 0; fn < 2; ++fn) {
                const int row = wn * 32 + fn * 16 + (lane & 15);
                const int byte = row * 256 + (((ks * 4 + (lane >> 4)) ^ (row & 15)) << 4);
                bh_[fn] = *(const short8*)(lds + F_KH + byte);
                bl[fn] = *(const short8*)(lds + F_KL + byte);
            }
            #pragma unroll
            for (int fm = 0; fm < 2; ++fm)
                #pragma unroll
                for (int fn = 0; fn < 2; ++fn) {
                    acc[nb][fm][fn] = __builtin_amdgcn_mfma_f32_16x16x32_bf16(ah[fm], bh_[fn], acc[nb][fm][fn], 0, 0, 0);
                    acc[nb][fm][fn] = __builtin_amdgcn_mfma_f32_16x16x32_bf16(al[fm], bh_[fn], acc[nb][fm][fn], 0, 0, 0);
                    acc[nb][fm][fn] = __builtin_amdgcn_mfma_f32_16x16x32_bf16(ah[fm], bl[fn], acc[nb][fm][fn], 0, 0, 0);
                }
        }
    }

    // ---- softmax over 256 cols (col>=255 masked)
    float pmax[2][4];
    #pragma unroll
    for (int fm = 0; fm < 2; ++fm)
        #pragma unroll
        for (int i = 0; i < 4; ++i) pmax[fm][i] = -1e30f;
    #pragma unroll
    for (int nb = 0; nb < 4; ++nb)
        #pragma unroll
        for (int fm = 0; fm < 2; ++fm)
            #pragma unroll
            for (int fn = 0; fn < 2; ++fn)
                #pragma unroll
                for (int i = 0; i < 4; ++i) {
                    const int col = nb * 64 + wn * 32 + fn * 16 + (lane & 15);
                    const float s = (col < TK) ? acc[nb][fm][fn][i] : -1e30f;
                    pmax[fm][i] = fmaxf(pmax[fm][i], s);
                }
    #pragma unroll
    for (int off = 1; off < 16; off <<= 1)
        #pragma unroll
        for (int fm = 0; fm < 2; ++fm)
            #pragma unroll
            for (int i = 0; i < 4; ++i) pmax[fm][i] = fmaxf(pmax[fm][i], __shfl_xor(pmax[fm][i], off));
    if ((lane & 15) == 0) {
        #pragma unroll
        for (int fm = 0; fm < 2; ++fm)
            #pragma unroll
            for (int i = 0; i < 4; ++i) {
                const int row = wm * 32 + fm * 16 + ((lane >> 4) << 2) + i;
                red[wn * 64 + row] = pmax[fm][i];
            }
    }
    __syncthreads();
    float rm[2][4];
    #pragma unroll
    for (int fm = 0; fm < 2; ++fm)
        #pragma unroll
        for (int i = 0; i < 4; ++i) {
            const int row = wm * 32 + fm * 16 + ((lane >> 4) << 2) + i;
            rm[fm][i] = fmaxf(red[row], red[64 + row]);
        }
    float psum[2][4] = {{0.f, 0.f, 0.f, 0.f}, {0.f, 0.f, 0.f, 0.f}};
    #pragma unroll
    for (int nb = 0; nb < 4; ++nb)
        #pragma unroll
        for (int fm = 0; fm < 2; ++fm)
            #pragma unroll
            for (int fn = 0; fn < 2; ++fn)
                #pragma unroll
                for (int i = 0; i < 4; ++i) {
                    const int col = nb * 64 + wn * 32 + fn * 16 + (lane & 15);
                    const int row = wm * 32 + fm * 16 + ((lane >> 4) << 2) + i;
                    float p = 0.f;
                    if (col < TK) p = __expf(acc[nb][fm][fn][i] - rm[fm][i]);
                    psum[fm][i] += p;
                    const unsigned short hp = f2bf(p);
                    const unsigned short lp = f2bf(p - bfbits2f(hp));
                    const int u = ((col >> 3) ^ ((row & 15) << 1));
                    const int byte = row * 512 + (u << 4) + (col & 7) * 2;
                    *(unsigned short*)(lds + F_PH + byte) = hp;
                    *(unsigned short*)(lds + F_PL + byte) = lp;
                }
    #pragma unroll
    for (int off = 1; off < 16; off <<= 1)
        #pragma unroll
        for (int fm = 0; fm < 2; ++fm)
            #pragma unroll
            for (int i = 0; i < 4; ++i) psum[fm][i] += __shfl_xor(psum[fm][i], off);
    if ((lane & 15) == 0) {
        #pragma unroll
        for (int fm = 0; fm < 2; ++fm)
            #pragma unroll
            for (int i = 0; i < 4; ++i) {
                const int row = wm * 32 + fm * 16 + ((lane >> 4) << 2) + i;
                red[128 + wn * 64 + row] = psum[fm][i];
            }
    }
    __syncthreads();
    if (wn == 0 && (lane & 15) == 0) {
        #pragma unroll
        for (int fm = 0; fm < 2; ++fm)
            #pragma unroll
            for (int i = 0; i < 4; ++i) {
                const int row = wm * 32 + fm * 16 + ((lane >> 4) << 2) + i;
                inv[row] = 1.f / (red[128 + row] + red[128 + 64 + row]);
            }
    }

    // ---- PV: O = P . V, 2-term (P hi+lo, V hi). Vt staged [128 d][64 n] in KH region.
    f32x4 accO[2][4];
    #pragma unroll
    for (int fm = 0; fm < 2; ++fm)
        #pragma unroll
        for (int fn = 0; fn < 4; ++fn)
            #pragma unroll
            for (int e = 0; e < 4; ++e) accO[fm][fn][e] = 0.f;

    #pragma unroll
    for (int nb = 0; nb < 4; ++nb) {
        __syncthreads();
        {   // transpose-stage V hi: Vt[d][n], pitch 128B, unit ^= d&7
            const int c4 = t & 31, r8 = t >> 5;
            #pragma unroll
            for (int rr = 0; rr < 8; ++rr) {
                const int nl = r8 + rr * 8;
                const int node = nb * 64 + nl;
                float4 f = make_float4(0.f, 0.f, 0.f, 0.f);
                if (node < TK) f = *(const float4*)(vp + (long)(node * 4 + b) * 1024 + h * 128 + c4 * 4);
                const float fa[4] = {f.x, f.y, f.z, f.w};
                #pragma unroll
                for (int j = 0; j < 4; ++j) {
                    const int d = c4 * 4 + j;
                    const int byte = d * 128 + ((((nl >> 3) ^ (d & 7)) << 4) | ((nl & 7) << 1));
                    *(unsigned short*)(lds + F_KH + byte) = f2bf(fa[j]);
                }
            }
        }
        __syncthreads();
        #pragma unroll
        for (int ks = 0; ks < 2; ++ks) {
            short8 pa[2], pl[2], vb[4];
            #pragma unroll
            for (int fm = 0; fm < 2; ++fm) {
                const int row = wm * 32 + fm * 16 + (lane & 15);
                const int u = (nb * 8 + ks * 4 + (lane >> 4)) ^ ((row & 15) << 1);
                const int byte = row * 512 + (u << 4);
                pa[fm] = *(const short8*)(lds + F_PH + byte);
                pl[fm] = *(const short8*)(lds + F_PL + byte);
            }
            #pragma unroll
            for (int fn = 0; fn < 4; ++fn) {
                const int d = wn * 64 + fn * 16 + (lane & 15);
                const int u = (ks * 4 + (lane >> 4)) ^ (d & 7);
                const int byte = d * 128 + (u << 4);
                vb[fn] = *(const short8*)(lds + F_KH + byte);
            }
            #pragma unroll
            for (int fm = 0; fm < 2; ++fm)
                #pragma unroll
                for (int fn = 0; fn < 4; ++fn) {
                    accO[fm][fn] = __builtin_amdgcn_mfma_f32_16x16x32_bf16(pa[fm], vb[fn], accO[fm][fn], 0, 0, 0);
                    accO[fm][fn] = __builtin_amdgcn_mfma_f32_16x16x32_bf16(pl[fm], vb[fn], accO[fm][fn], 0, 0, 0);
                }
        }
    }

    // ---- epilogue: normalize + write packed bf16 [hi|lo] attn rows directly
    __syncthreads();
    #pragma unroll
    for (int fm = 0; fm < 2; ++fm)
        #pragma unroll
        for (int i = 0; i < 4; ++i) {
            const int row = wm * 32 + fm * 16 + ((lane >> 4) << 2) + i;
            const float iv = inv[row];
            const int arow = (qh * 64 + row) * 4 + b;
            #pragma unroll
            for (int fn = 0; fn < 4; ++fn) {
                const int col = h * 128 + wn * 64 + fn * 16 + (lane & 15);
                const float val = accO[fm][fn][i] * iv;
                const unsigned short hv = f2bf(val);
                const unsigned short lv = f2bf(val - bfbits2f(hv));
                apk2[(long)arow * 2048 + col] = hv;
                apk2[(long)arow * 2048 + 1024 + col] = lv;
            }
        }
}

extern "C" void kernel_launch(void* const* d_in, const int* in_sizes, int n_in,
                              void* d_out, int out_size, void* d_ws, size_t ws_size,
                              hipStream_t stream) {
    const float* query   = (const float*)d_in[0];
    const float* key_t   = (const float*)d_in[1];
    const float* value   = (const float*)d_in[2];
    const int*   indices = (const int*)d_in[3];
    const float* ipw     = (const float*)d_in[4];
    const float* ipb     = (const float*)d_in[5];
    const float* opw     = (const float*)d_in[6];
    const float* opb     = (const float*)d_in[7];
    float* out = (float*)d_out;

    float* ws = (float*)d_ws;
    float* kp   = ws;                        // [1024][1024]
    float* vp   = kp + 1048576;              // [1024][1024]
    float* qp   = vp + 1048576;              // [512][1024]
    float* sbuf = qp + 524288;               // [4][256][1024] suffix sums
    unsigned short* apk  = (unsigned short*)(sbuf + 1048576);  // [2560][2048]
    unsigned short* wpk  = apk + 2560L * 2048;                 // [4096][2048]
    unsigned short* apk2 = apk;              // overlay (apk dead after qkvb)

    const float qscale = 0.08838834764831843f;  // 128^-0.5

    pack_all<<<dim3(2048), 256, 0, stream>>>(query, key_t, value, ipw, opw, apk, wpk);

    qkvb_kernel<<<dim3(16, 40), 256, 0, stream>>>(apk, wpk, ipb, qp, kp, vp, qscale);

    ksuffix_kernel<<<dim3(32, 4), 256, 0, stream>>>(kp, sbuf);

    fused_attn_kernel<<<dim3(64), 256, 0, stream>>>(qp, sbuf, vp, indices, apk2);

    outprojb_kernel<<<dim3(16, 16), 256, 0, stream>>>(apk2, wpk, opb, out);
}